// Round 1
// baseline (737.815 us; speedup 1.0000x reference)
//
#include <hip/hip_runtime.h>
#include <math.h>

#define EPSF 1e-8f
#define BM 64
#define BN 64
#define BK 36
#define LDT 68   // padded k-major LDS leading dim (multiple of 4 -> float4 aligned)

__device__ __forceinline__ unsigned int ord_from_float(float f) {
  unsigned int u = __float_as_uint(f);
  return (u & 0x80000000u) ? ~u : (u | 0x80000000u);
}

__device__ __forceinline__ float float_from_ord(unsigned int o) {
  return (o & 0x80000000u) ? __uint_as_float(o & 0x7fffffffu)
                           : __uint_as_float(~o);
}

__device__ __forceinline__ unsigned long long shfl_xor_u64(unsigned long long x, int m) {
  int lo = __shfl_xor((int)(unsigned int)(x & 0xffffffffull), m, 64);
  int hi = __shfl_xor((int)(unsigned int)(x >> 32), m, 64);
  return ((unsigned long long)(unsigned int)hi << 32) | (unsigned int)lo;
}

__global__ __launch_bounds__(64) void rowsum_kernel(const float* __restrict__ inp,
                                                    float* __restrict__ s_in,
                                                    int N, int D) {
  int i = blockIdx.x;
  float s = 0.f;
  for (int d = threadIdx.x; d < D; d += 64) s += inp[(size_t)i * D + d];
  #pragma unroll
  for (int m = 1; m < 64; m <<= 1) s += __shfl_xor(s, m, 64);
  if (threadIdx.x == 0) s_in[i] = s;
}

__global__ __launch_bounds__(64) void stirling_kernel(const float* __restrict__ tgt,
                                                      float* __restrict__ s_st,
                                                      int M, int D) {
  int j = blockIdx.x;
  float s = 0.f;
  for (int d = threadIdx.x; d < D; d += 64) {
    float t = tgt[(size_t)j * D + d];
    if (t > 1.0f)
      s += t * logf(t) - t + 0.5f * logf(6.283185307179586f * t);
  }
  #pragma unroll
  for (int m = 1; m < 64; m <<= 1) s += __shfl_xor(s, m, 64);
  if (threadIdx.x == 0) s_st[j] = s;
}

// Computes cross = log_in @ tgt^T tile-by-tile, fuses val = s_st[j] - cross[i,j],
// reduces min+argmin over the block's j-range, atomicMin-combines per row.
__global__ __launch_bounds__(256) void pair_min_kernel(
    const float* __restrict__ inp, const float* __restrict__ tgt,
    const float* __restrict__ s_st, unsigned long long* __restrict__ packed,
    int N, int M, int D) {
  __shared__ float As[BK][LDT];
  __shared__ float Bs[BK][LDT];
  const int row0 = blockIdx.y * BM;
  const int col0 = blockIdx.x * BN;
  const int t = threadIdx.x;
  const int tx = t & 15;
  const int ty = t >> 4;

  float acc[4][4];
  #pragma unroll
  for (int u = 0; u < 4; ++u)
    #pragma unroll
    for (int v = 0; v < 4; ++v) acc[u][v] = 0.f;

  for (int k0 = 0; k0 < D; k0 += BK) {
    const int kc = min(BK, D - k0);
    // stage A (log on the fly) and B tiles, k-major
    for (int e = t; e < BM * BK; e += 256) {
      int i = e / BK;
      int k = e - i * BK;
      float a = 0.f, b = 0.f;
      if (k < kc) {
        int gk = k0 + k;
        int gi = row0 + i;
        if (gi < N) a = logf(inp[(size_t)gi * D + gk] + EPSF);
        int gj = col0 + i;
        if (gj < M) b = tgt[(size_t)gj * D + gk];
      }
      As[k][i] = a;
      Bs[k][i] = b;
    }
    __syncthreads();
    #pragma unroll 4
    for (int k = 0; k < kc; ++k) {
      float4 a4 = *(const float4*)(&As[k][ty * 4]);
      float4 b4 = *(const float4*)(&Bs[k][tx * 4]);
      float av[4] = {a4.x, a4.y, a4.z, a4.w};
      float bv[4] = {b4.x, b4.y, b4.z, b4.w};
      #pragma unroll
      for (int u = 0; u < 4; ++u)
        #pragma unroll
        for (int v = 0; v < 4; ++v)
          acc[u][v] = fmaf(av[u], bv[v], acc[u][v]);
    }
    __syncthreads();
  }

  // fused min/argmin over this block's j columns
  float stv[4];
  #pragma unroll
  for (int v = 0; v < 4; ++v) {
    int gj = col0 + tx * 4 + v;
    stv[v] = (gj < M) ? s_st[gj] : 0.f;
  }
  #pragma unroll
  for (int u = 0; u < 4; ++u) {
    unsigned long long bst = ~0ull;
    #pragma unroll
    for (int v = 0; v < 4; ++v) {
      int gj = col0 + tx * 4 + v;
      if (gj < M) {
        float val = stv[v] - acc[u][v];  // s_in[i] added in finalize (j-independent)
        unsigned long long p =
            ((unsigned long long)ord_from_float(val) << 32) | (unsigned int)gj;
        bst = p < bst ? p : bst;
      }
    }
    // reduce across the 16 lanes (same ty -> same row i), all within one wave
    #pragma unroll
    for (int m = 1; m < 16; m <<= 1) {
      unsigned long long o = shfl_xor_u64(bst, m);
      bst = o < bst ? o : bst;
    }
    int gi = row0 + ty * 4 + u;
    if (tx == 0 && gi < N) atomicMin(&packed[gi], bst);
  }
}

__global__ __launch_bounds__(256) void finalize_kernel(
    const unsigned long long* __restrict__ packed,
    const float* __restrict__ s_in, float* __restrict__ out, int N) {
  __shared__ double sh[256];
  double s = 0.0;
  for (int i = threadIdx.x; i < N; i += 256) {
    unsigned long long p = packed[i];
    float val = float_from_ord((unsigned int)(p >> 32));
    out[1 + i] = (float)(unsigned int)(p & 0xffffffffull);
    s += (double)(s_in[i] + val);
  }
  sh[threadIdx.x] = s;
  __syncthreads();
  for (int off = 128; off > 0; off >>= 1) {
    if (threadIdx.x < off) sh[threadIdx.x] += sh[threadIdx.x + off];
    __syncthreads();
  }
  if (threadIdx.x == 0) out[0] = (float)(sh[0] / N);
}

extern "C" void kernel_launch(void* const* d_in, const int* in_sizes, int n_in,
                              void* d_out, int out_size, void* d_ws, size_t ws_size,
                              hipStream_t stream) {
  const float* inp = (const float*)d_in[0];
  const float* tgt = (const float*)d_in[1];
  float* out = (float*)d_out;

  int N = out_size - 1;           // outputs: [loss scalar, match[N]]
  int D = in_sizes[0] / N;
  int M = in_sizes[1] / D;

  float* s_in = (float*)d_ws;
  float* s_st = s_in + N;
  unsigned long long* packed = (unsigned long long*)(s_st + M);  // (N+M)*4 offset, 8B-aligned

  hipMemsetAsync(packed, 0xFF, (size_t)N * sizeof(unsigned long long), stream);
  rowsum_kernel<<<N, 64, 0, stream>>>(inp, s_in, N, D);
  stirling_kernel<<<M, 64, 0, stream>>>(tgt, s_st, M, D);

  dim3 grid((M + BN - 1) / BN, (N + BM - 1) / BM);
  pair_min_kernel<<<grid, 256, 0, stream>>>(inp, tgt, s_st, packed, N, M, D);

  finalize_kernel<<<1, 256, 0, stream>>>(packed, s_in, out, N);
}